// Round 8
// baseline (163.012 us; speedup 1.0000x reference)
//
#include <hip/hip_runtime.h>
#include <hip/hip_bf16.h>

typedef __attribute__((ext_vector_type(8))) short short8;
typedef __attribute__((ext_vector_type(4))) float f32x4;

#define LN_EPS 1e-5f

__device__ __forceinline__ unsigned short f2bf(float f) {
  union { float f; unsigned u; } v; v.f = f;
  unsigned r = v.u + 0x7FFFu + ((v.u >> 16) & 1u);
  return (unsigned short)(r >> 16);
}

// Swizzled byte address into A tile: row in [0,32), colb in [0,1536) bytes.
__device__ __forceinline__ int a_addr(int row, int colb) {
  return row * 1536 + (colb ^ ((row & 7) << 4));
}

// x: (2, 96, 32, 128, 128) f32 ; w: (192, 768) f32 ; out: (2, 192, 16, 64, 64) f32
// k' = (dd*2+hh)*192 + c*2 + ww   (orig k = (dd*2+hh)*192 + ww*96 + c)
// Weights pre-swizzled to MFMA B-frag order: [NT(12)][ks(24)][lane(64)][8 bf16]

__global__ __launch_bounds__(256) void pm_prep(
    const float* __restrict__ w, const float* __restrict__ g,
    const float* __restrict__ be, unsigned short* __restrict__ wg,
    float* __restrict__ sb) {
  const int o = blockIdx.x;
  const int t = threadIdx.x;
  const int lane = t & 63, wv = t >> 6;
  __shared__ float red[4][2];
  float sa = 0.f, ba = 0.f;
#pragma unroll
  for (int u = 0; u < 3; ++u) {
    int kp = t + 256 * u;
    int dh = kp / 192;
    int rem = kp - dh * 192;
    int c = rem >> 1, ww = rem & 1;
    int k = dh * 192 + ww * 96 + c;
    float wv_ = w[o * 768 + k];
    float v = wv_ * g[k];
    sa += v;
    ba += wv_ * be[k];
    int NT = o >> 4, ks = kp >> 5, qq = (kp >> 3) & 3, jj = kp & 7;
    wg[(((NT * 24 + ks) * 64) + qq * 16 + (o & 15)) * 8 + jj] = f2bf(v);
  }
#pragma unroll
  for (int d = 1; d < 64; d <<= 1) {
    sa += __shfl_xor(sa, d);
    ba += __shfl_xor(ba, d);
  }
  if (lane == 0) { red[wv][0] = sa; red[wv][1] = ba; }
  __syncthreads();
  if (t == 0) {
    sb[o] = red[0][0] + red[1][0] + red[2][0] + red[3][0];
    sb[192 + o] = red[0][1] + red[1][1] + red[2][1] + red[3][1];
  }
}

__global__ __launch_bounds__(256, 3) void pm_main(
    const float* __restrict__ x, const unsigned short* __restrict__ wg,
    const float* __restrict__ sb, float* __restrict__ out) {
  const int bid = blockIdx.x;       // 4096 = (b, d2, h2, wh)
  const int wh = bid & 1;
  const int h2 = (bid >> 1) & 63;
  const int d2 = (bid >> 7) & 15;
  const int b = bid >> 11;
  const int t = threadIdx.x;
  const int lane = t & 63, wv = t >> 6;
  const int q = lane & 15, sc = lane >> 4;

  __shared__ __align__(16) unsigned char A_lds[32 * 1536];  // 48 KB swizzled
  __shared__ float part[4][32][2];
  __shared__ float stats[32][2];

  const float* xb = x + (size_t)b * (96 * 32 * 128 * 128);
  const int cp0 = wv * 12 + sc * 3;          // channel-pair base for this lane
  const float* pc[3];
#pragma unroll
  for (int i = 0; i < 3; ++i)
    pc[i] = xb + (size_t)(2 * (cp0 + i)) * 524288 + wh * 64 + 4 * q;

  float sum0 = 0.f, sq0 = 0.f, sum1 = 0.f, sq1 = 0.f;
  float4 xa[2][3], xc[2][3];   // 2-phase-deep in-flight window (statically indexed)

  auto issue = [&](int p, int buf) {
    int off = (2 * d2 + (p >> 1)) * 16384 + (2 * h2 + (p & 1)) * 128;
#pragma unroll
    for (int i = 0; i < 3; ++i) {
      xa[buf][i] = *(const float4*)(pc[i] + off);
      xc[buf][i] = *(const float4*)(pc[i] + 524288 + off);
    }
  };

  auto consume = [&](int p, int buf) {
#pragma unroll
    for (int i = 0; i < 3; ++i) {
      float4 f0 = xa[buf][i], f1 = xc[buf][i];
      sum0 += (f0.x + f0.y) + (f1.x + f1.y);
      sq0  += f0.x * f0.x + f0.y * f0.y + f1.x * f1.x + f1.y * f1.y;
      sum1 += (f0.z + f0.w) + (f1.z + f1.w);
      sq1  += f0.z * f0.z + f0.w * f0.w + f1.z * f1.z + f1.w * f1.w;
      int colb = p * 384 + 8 * (cp0 + i);
      *(ushort4*)&A_lds[a_addr(2 * q, colb)] =
          make_ushort4(f2bf(f0.x), f2bf(f0.y), f2bf(f1.x), f2bf(f1.y));
      *(ushort4*)&A_lds[a_addr(2 * q + 1, colb)] =
          make_ushort4(f2bf(f0.z), f2bf(f0.w), f2bf(f1.z), f2bf(f1.w));
    }
  };

  const int al = lane & 15, ah = lane >> 4;
  const short8* wgs = (const short8*)wg;
  f32x4 acc[2][3];
#pragma unroll
  for (int mt = 0; mt < 2; ++mt)
#pragma unroll
    for (int nt = 0; nt < 3; ++nt) acc[mt][nt] = {0.f, 0.f, 0.f, 0.f};

  issue(0, 0);
  issue(1, 1);

#pragma unroll
  for (int p = 0; p < 4; ++p) {
    const int buf = p & 1;
    consume(p, buf);
    if (p == 3) {
      // reduce LN partials over sc (lane bits 4,5)
      sum0 += __shfl_xor(sum0, 16); sum0 += __shfl_xor(sum0, 32);
      sq0  += __shfl_xor(sq0, 16);  sq0  += __shfl_xor(sq0, 32);
      sum1 += __shfl_xor(sum1, 16); sum1 += __shfl_xor(sum1, 32);
      sq1  += __shfl_xor(sq1, 16);  sq1  += __shfl_xor(sq1, 32);
      if (sc == 0) {
        part[wv][2 * q][0] = sum0;     part[wv][2 * q][1] = sq0;
        part[wv][2 * q + 1][0] = sum1; part[wv][2 * q + 1][1] = sq1;
      }
    }
    __syncthreads();

    // B-fragments for this phase FIRST (in-order vmcnt: MFMA waits only on B)
    short8 bfr[6][3];
#pragma unroll
    for (int ksi = 0; ksi < 6; ++ksi)
#pragma unroll
      for (int nt = 0; nt < 3; ++nt)
        bfr[ksi][nt] = wgs[((wv * 3 + nt) * 24 + (p * 6 + ksi)) * 64 + lane];

    if (p < 2) issue(p + 2, buf);  // 2-phase-deep: lands by consume(p+2)

    if (p == 3) {
      int row = t & 31;
      float S = part[0][row][0] + part[1][row][0] + part[2][row][0] + part[3][row][0];
      float Q = part[0][row][1] + part[1][row][1] + part[2][row][1] + part[3][row][1];
      float mu = S * (1.f / 768.f);
      float var = Q * (1.f / 768.f) - mu * mu;
      float rs = rsqrtf(var + LN_EPS);
      stats[row][0] = rs;
      stats[row][1] = mu * rs;
    }

#pragma unroll
    for (int ksi = 0; ksi < 6; ++ksi) {
      int ks = p * 6 + ksi;
      short8 afr[2];
#pragma unroll
      for (int mt = 0; mt < 2; ++mt)
        afr[mt] = *(const short8*)&A_lds[a_addr(mt * 16 + al, ks * 64 + ah * 16)];
#pragma unroll
      for (int nt = 0; nt < 3; ++nt)
#pragma unroll
        for (int mt = 0; mt < 2; ++mt)
          acc[mt][nt] = __builtin_amdgcn_mfma_f32_16x16x32_bf16(afr[mt], bfr[ksi][nt], acc[mt][nt], 0, 0, 0);
    }
  }
  __syncthreads();

  // epilogue: y = rs*acc - (mu*rs)*S[o] + bias[o]
#pragma unroll
  for (int nt = 0; nt < 3; ++nt) {
    int o = wv * 48 + nt * 16 + al;
    float Sv = sb[o], Bv = sb[192 + o];
    float* ob = out + (((size_t)(b * 192 + o) * 16 + d2) * 64 + h2) * 64 + wh * 32;
#pragma unroll
    for (int mt = 0; mt < 2; ++mt) {
      int m0 = mt * 16 + ah * 4;
      float4 y;
      y.x = stats[m0 + 0][0] * acc[mt][nt][0] - stats[m0 + 0][1] * Sv + Bv;
      y.y = stats[m0 + 1][0] * acc[mt][nt][1] - stats[m0 + 1][1] * Sv + Bv;
      y.z = stats[m0 + 2][0] * acc[mt][nt][2] - stats[m0 + 2][1] * Sv + Bv;
      y.w = stats[m0 + 3][0] * acc[mt][nt][3] - stats[m0 + 3][1] * Sv + Bv;
      *(float4*)(ob + m0) = y;
    }
  }
}

extern "C" void kernel_launch(void* const* d_in, const int* in_sizes, int n_in,
                              void* d_out, int out_size, void* d_ws, size_t ws_size,
                              hipStream_t stream) {
  (void)in_sizes; (void)n_in; (void)out_size; (void)ws_size;
  const float* x  = (const float*)d_in[0];
  const float* w  = (const float*)d_in[1];
  const float* g  = (const float*)d_in[2];
  const float* be = (const float*)d_in[3];
  unsigned short* wg = (unsigned short*)d_ws;
  float* sb = (float*)((char*)d_ws + 192 * 768 * sizeof(unsigned short));
  pm_prep<<<192, 256, 0, stream>>>(w, g, be, wg, sb);
  pm_main<<<4096, 256, 0, stream>>>(x, wg, sb, (float*)d_out);
}